// Round 2
// baseline (156.382 us; speedup 1.0000x reference)
//
#include <hip/hip_runtime.h>

typedef __bf16 bf16x8 __attribute__((ext_vector_type(8)));
typedef float f32x4 __attribute__((ext_vector_type(4)));

__device__ __forceinline__ ushort f2bf(float f) {
    union { float f; unsigned u; } v; v.f = f;
    unsigned r = v.u + 0x7FFF + ((v.u >> 16) & 1);
    return (ushort)(r >> 16);
}

__device__ __forceinline__ void async_copy16(const void* g, void* l) {
    __builtin_amdgcn_global_load_lds(
        (const __attribute__((address_space(1))) void*)g,
        (__attribute__((address_space(3))) void*)l, 16, 0, 0);
}

// ---------------- cvt: x -> bf16, [Wq;Wk] -> bf16, [bq;bk] -> f32 concat ----
__global__ __launch_bounds__(256) void cvt_kernel(
    const float4* __restrict__ x, const float4* __restrict__ Wq,
    const float4* __restrict__ Wk, const float4* __restrict__ bq,
    const float4* __restrict__ bk,
    ushort4* __restrict__ xb, ushort4* __restrict__ Wb,
    float4* __restrict__ biasc) {
    int i = blockIdx.x * 256 + threadIdx.x;
    if (i < 2097152) {
        float4 v = x[i];
        ushort4 r; r.x = f2bf(v.x); r.y = f2bf(v.y); r.z = f2bf(v.z); r.w = f2bf(v.w);
        xb[i] = r;
    }
    if (i < 131072) {
        float4 v = (i < 65536) ? Wq[i] : Wk[i - 65536];
        ushort4 r; r.x = f2bf(v.x); r.y = f2bf(v.y); r.z = f2bf(v.z); r.w = f2bf(v.w);
        Wb[i] = r;
    }
    if (i < 256) {
        biasc[i] = (i < 128) ? bq[i] : bk[i - 128];
    }
}

// ---------------- fold: xzT[b][d][n] = bf16(x[b][n][d] / Z[b][n]) ----------
__global__ __launch_bounds__(256) void fold_kernel(
    const float* __restrict__ x, const float* __restrict__ Z,
    ushort* __restrict__ xzT) {
    __shared__ float tile[64][65];
    __shared__ float zin[64];
    const int b = blockIdx.y;
    const int td = blockIdx.x & 7;
    const int tn = blockIdx.x >> 3;
    const int n0 = tn * 64, d0 = td * 64;
    const int t = threadIdx.x;
    if (t < 64) zin[t] = 1.0f / Z[b * 2048 + n0 + t];
    __syncthreads();
    const int c = t & 63, r0 = t >> 6;
#pragma unroll
    for (int j = 0; j < 16; ++j) {
        int r = r0 + j * 4;
        tile[r][c] = x[((size_t)b * 2048 + n0 + r) * 512 + d0 + c] * zin[r];
    }
    __syncthreads();
#pragma unroll
    for (int j = 0; j < 16; ++j) {
        int dr = r0 + j * 4;
        xzT[((size_t)b * 512 + d0 + dr) * 2048 + n0 + c] = f2bf(tile[c][dr]);
    }
}

// ---------------- 8-phase bt-GEMM: C[m,n] = sum_k A[m,k]*B[n,k] -------------
// BM=256, BK=64 (two K-halves of 32 elems). 8 waves (2 M x 4 N), per-wave
// output 128 x (BN/4). LDS: A [db][ks][256][64B], B [db][ks][BN][64B].
// Swizzle (both sides): kbyte ^= ((row&6)<<3). Counted vmcnt, never 0.
// EPI 0: +bias, bf16 store | EPI 1: exp*scale, bf16 store + Z colsum | EPI 2: f32 store
template <int BN, int EPI>
__global__ __launch_bounds__(512, 2) void gemm8(
    const ushort* __restrict__ A, int lda, long sA,
    const ushort* __restrict__ B, int ldb, long sB,
    void* __restrict__ C, int ldc, long sC,
    int tiles_n, int K,
    const float* __restrict__ bias, float scale,
    float* __restrict__ Z, long sZ) {
    constexpr int NREP = BN / 64;     // 4 or 2
    constexpr int JW = NREP / 2;      // 2 or 1
    constexpr int LB = BN / 128;      // B loads/half/thread: 2 or 1
    constexpr int VMN = 4 + 2 * LB;   // counted vmcnt: 8 or 6
    constexpr int ABUF = 32768;       // per-db A bytes
    constexpr int BHALF = BN * 64;    // per-ks B bytes
    constexpr int BBUF = 2 * BHALF;
    extern __shared__ char smem[];
    char* lA = smem;                  // 2*ABUF
    char* lB = smem + 2 * ABUF;       // 2*BBUF

    const int b = blockIdx.y;
    const ushort* Ag = A + (size_t)b * sA;
    const ushort* Bg = B + (size_t)b * sB;
    const int tm = blockIdx.x / tiles_n, tn = blockIdx.x % tiles_n;
    const int t = threadIdx.x;
    const int l = t & 63, w = t >> 6;
    const int wr = w >> 2, wc = w & 3;
    const int NT = K >> 6;

    // per-thread staging offsets (linear LDS dest, pre-swizzled global source)
    size_t gA[2]; int dA[2];
#pragma unroll
    for (int p = 0; p < 2; ++p) {
        int off = p * 8192 + t * 16;
        int row = off >> 6, kb = off & 63;
        int kbs = kb ^ ((row & 6) << 3);
        gA[p] = (size_t)(tm * 256 + row) * lda + (kbs >> 1);
        dA[p] = off;
    }
    size_t gB[LB]; int dB[LB];
#pragma unroll
    for (int p = 0; p < LB; ++p) {
        int off = p * 8192 + t * 16;
        int row = off >> 6, kb = off & 63;
        int kbs = kb ^ ((row & 6) << 3);
        gB[p] = (size_t)(tn * BN + row) * ldb + (kbs >> 1);
        dB[p] = off;
    }

    auto stageA = [&](int db, int ks, int ktt) {
        if (ktt > NT - 1) ktt = NT - 1;
        const ushort* s0 = Ag + ktt * 64 + ks * 32;
#pragma unroll
        for (int p = 0; p < 2; ++p)
            async_copy16(s0 + gA[p], lA + db * ABUF + ks * 16384 + dA[p]);
    };
    auto stageB = [&](int db, int ks, int ktt) {
        if (ktt > NT - 1) ktt = NT - 1;
        const ushort* s0 = Bg + ktt * 64 + ks * 32;
#pragma unroll
        for (int p = 0; p < LB; ++p)
            async_copy16(s0 + gB[p], lB + db * BBUF + ks * BHALF + dB[p]);
    };

    // lane-constant part of fragment LDS addresses (swizzled)
    const int lan = (l & 15) * 64 + ((((l >> 4)) ^ ((l >> 1) & 3)) << 4);

    f32x4 acc[8][NREP];
#pragma unroll
    for (int i = 0; i < 8; ++i)
#pragma unroll
        for (int j = 0; j < NREP; ++j) acc[i][j] = (f32x4){0.f, 0.f, 0.f, 0.f};

    // prologue: A0(0) B0(0) A1(0) B1(0) A0(1) B0(1)
    stageA(0, 0, 0); stageB(0, 0, 0);
    stageA(0, 1, 0); stageB(0, 1, 0);
    stageA(1, 0, 1); stageB(1, 0, 1);
    asm volatile("s_waitcnt vmcnt(%0)" :: "n"(VMN) : "memory");
    __builtin_amdgcn_s_barrier();
    __builtin_amdgcn_sched_barrier(0);

    for (int kt = 0; kt < NT; ++kt) {
        const int db = kt & 1;
        bf16x8 a[8];
#pragma unroll
        for (int ph = 0; ph < 4; ++ph) {
            const int ks = ph >> 1;                       // 0,0,1,1
            const int js = (ph == 1 || ph == 2) ? 1 : 0;  // 0,1,1,0
            if (ph == 0 || ph == 2) {
#pragma unroll
                for (int i = 0; i < 8; ++i)
                    a[i] = *(const bf16x8*)(lA + db * ABUF + ks * 16384 +
                                            wr * 8192 + i * 1024 + lan);
            }
            bf16x8 bb[JW];
#pragma unroll
            for (int j = 0; j < JW; ++j)
                bb[j] = *(const bf16x8*)(lB + db * BBUF + ks * BHALF +
                                         wc * (BN / 4) * 64 + (js * JW + j) * 1024 + lan);
            if (ph == 0)      stageA(db ^ 1, 1, kt + 1);
            else if (ph == 1) stageB(db ^ 1, 1, kt + 1);
            else if (ph == 2) stageA(db, 0, kt + 2);
            else              stageB(db, 0, kt + 2);
            __builtin_amdgcn_sched_barrier(0);
            if (ph == 1 || ph == 3)
                asm volatile("s_waitcnt vmcnt(%0)" :: "n"(VMN) : "memory");
            __builtin_amdgcn_s_barrier();
            __builtin_amdgcn_s_setprio(1);
#pragma unroll
            for (int i = 0; i < 8; ++i)
#pragma unroll
                for (int j = 0; j < JW; ++j)
                    acc[i][js * JW + j] = __builtin_amdgcn_mfma_f32_16x16x32_bf16(
                        a[i], bb[j], acc[i][js * JW + j], 0, 0, 0);
            __builtin_amdgcn_s_setprio(0);
            __builtin_amdgcn_s_barrier();
            __builtin_amdgcn_sched_barrier(0);
        }
    }
    asm volatile("s_waitcnt vmcnt(0)" ::: "memory");  // drain tail prefetches

    const int mb = tm * 256 + wr * 128;
    const int nb = tn * BN + wc * (BN / 4);

    if (EPI == 0) {
        ushort* Cp = (ushort*)C + (size_t)b * sC;
#pragma unroll
        for (int i = 0; i < 8; ++i)
#pragma unroll
            for (int j = 0; j < NREP; ++j)
#pragma unroll
                for (int q = 0; q < 4; ++q) {
                    int row = mb + i * 16 + (l >> 4) * 4 + q;
                    int col = nb + j * 16 + (l & 15);
                    Cp[(size_t)row * ldc + col] = f2bf(acc[i][j][q] + bias[col]);
                }
    } else if (EPI == 1) {
        ushort* Cp = (ushort*)C + (size_t)b * sC;
        float colsum[NREP];
#pragma unroll
        for (int j = 0; j < NREP; ++j) colsum[j] = 0.f;
#pragma unroll
        for (int i = 0; i < 8; ++i)
#pragma unroll
            for (int j = 0; j < NREP; ++j)
#pragma unroll
                for (int q = 0; q < 4; ++q) {
                    int row = mb + i * 16 + (l >> 4) * 4 + q;
                    int col = nb + j * 16 + (l & 15);
                    float e = __expf(acc[i][j][q] * scale);
                    Cp[(size_t)row * ldc + col] = f2bf(e);
                    colsum[j] += e;
                }
#pragma unroll
        for (int j = 0; j < NREP; ++j) {
            float s = colsum[j];
            s += __shfl_xor(s, 16);
            s += __shfl_xor(s, 32);
            if (l < 16) atomicAdd(&Z[b * sZ + nb + j * 16 + l], s);
        }
    } else {
        float* Cp = (float*)C + (size_t)b * sC;
#pragma unroll
        for (int i = 0; i < 8; ++i)
#pragma unroll
            for (int j = 0; j < NREP; ++j)
#pragma unroll
                for (int q = 0; q < 4; ++q) {
                    int row = mb + i * 16 + (l >> 4) * 4 + q;
                    int col = nb + j * 16 + (l & 15);
                    Cp[(size_t)row * ldc + col] = acc[i][j][q];
                }
    }
}

namespace {
struct AttrInit {
    AttrInit() {
        hipFuncSetAttribute(reinterpret_cast<const void*>(&gemm8<256, 0>),
                            hipFuncAttributeMaxDynamicSharedMemorySize, 131072);
        hipFuncSetAttribute(reinterpret_cast<const void*>(&gemm8<256, 1>),
                            hipFuncAttributeMaxDynamicSharedMemorySize, 131072);
        hipFuncSetAttribute(reinterpret_cast<const void*>(&gemm8<128, 2>),
                            hipFuncAttributeMaxDynamicSharedMemorySize, 98304);
    }
};
AttrInit attr_init_;
}

extern "C" void kernel_launch(void* const* d_in, const int* in_sizes, int n_in,
                              void* d_out, int out_size, void* d_ws, size_t ws_size,
                              hipStream_t stream) {
    const float* x  = (const float*)d_in[0];
    const float* Wq = (const float*)d_in[1];
    const float* bq = (const float*)d_in[2];
    const float* Wk = (const float*)d_in[3];
    const float* bk = (const float*)d_in[4];

    char* ws = (char*)d_ws;
    ushort* xb    = (ushort*)(ws);                 // 16 MB (reused as xzT)
    ushort* Wb    = (ushort*)(ws + 16777216);      //  1 MB
    float*  biasc = (float*) (ws + 17825792);      //  4 KB
    float*  Z     = (float*) (ws + 17829888);      // 64 KB
    ushort* qkb   = (ushort*)(ws + 17895424);      // 32 MB
    ushort* E     = (ushort*)(ws + 51449856);      // 64 MB
    ushort* xzT   = xb;

    hipMemsetAsync(Z, 0, 16384 * 4, stream);

    cvt_kernel<<<8192, 256, 0, stream>>>(
        (const float4*)x, (const float4*)Wq, (const float4*)Wk,
        (const float4*)bq, (const float4*)bk,
        (ushort4*)xb, (ushort4*)Wb, (float4*)biasc);

    // proj: qk[m, 0:1024] = x[m,:] . W[h,:] + bias   (M=16384, N=1024, K=512)
    gemm8<256, 0><<<dim3(256, 1), 512, 131072, stream>>>(
        xb, 512, 0L, Wb, 512, 0L, qkb, 1024, 0L,
        4, 512, biasc, 0.f, nullptr, 0L);

    // E-pass: E[b][m][n] = exp(scale * k[m].q[n]); Z[b][n] += column sums
    gemm8<256, 1><<<dim3(64, 8), 512, 131072, stream>>>(
        qkb + 512, 1024, 2048L * 1024, qkb, 1024, 2048L * 1024,
        E, 2048, 2048L * 2048, 8, 512,
        nullptr, 0.04419417382415922f, Z, 2048L);

    // fold: xzT[b][d][n] = bf16(x[b][n][d] / Z[b][n])
    fold_kernel<<<dim3(256, 8), 256, 0, stream>>>(x, Z, xzT);

    // out: out[b][m][d] = sum_n E[b][m][n] * xzT[b][d][n]   (fp32 store)
    gemm8<128, 2><<<dim3(32, 8), 512, 98304, stream>>>(
        E, 2048, 2048L * 2048, xzT, 2048, 512L * 2048,
        d_out, 512, 2048L * 512, 4, 2048,
        nullptr, 0.f, nullptr, 0L);
}

// Round 3
// 153.849 us; speedup vs baseline: 1.0165x; 1.0165x over previous
//
#include <hip/hip_runtime.h>

typedef __bf16 bf16x8 __attribute__((ext_vector_type(8)));
typedef float f32x16 __attribute__((ext_vector_type(16)));

__device__ __forceinline__ ushort f2bf(float f) {
    union { float f; unsigned u; } v; v.f = f;
    unsigned r = v.u + 0x7FFF + ((v.u >> 16) & 1);
    return (ushort)(r >> 16);
}
__device__ __forceinline__ float bf2f(ushort u) {
    union { unsigned u; float f; } v; v.u = ((unsigned)u) << 16;
    return v.f;
}

__device__ __forceinline__ void async_copy16(const void* g, void* l) {
    __builtin_amdgcn_global_load_lds(
        (const __attribute__((address_space(1))) void*)g,
        (__attribute__((address_space(3))) void*)l, 16, 0, 0);
}

// ---------------- cvt: x -> bf16, [Wq;Wk] -> bf16, [bq;bk] -> f32 concat ----
__global__ __launch_bounds__(256) void cvt_kernel(
    const float4* __restrict__ x, const float4* __restrict__ Wq,
    const float4* __restrict__ Wk, const float4* __restrict__ bq,
    const float4* __restrict__ bk,
    ushort4* __restrict__ xb, ushort4* __restrict__ Wb,
    float4* __restrict__ biasc) {
    int i = blockIdx.x * 256 + threadIdx.x;
    if (i < 2097152) {
        float4 v = x[i];
        ushort4 r; r.x = f2bf(v.x); r.y = f2bf(v.y); r.z = f2bf(v.z); r.w = f2bf(v.w);
        xb[i] = r;
    }
    if (i < 131072) {
        float4 v = (i < 65536) ? Wq[i] : Wk[i - 65536];
        ushort4 r; r.x = f2bf(v.x); r.y = f2bf(v.y); r.z = f2bf(v.z); r.w = f2bf(v.w);
        Wb[i] = r;
    }
    if (i < 256) {
        biasc[i] = (i < 128) ? bq[i] : bk[i - 128];
    }
}

// ---------------- fold: xzT[b][d][n] = bf16(xb[b][n][d] / Z[b][n]) ---------
// reads bf16 xb (vectorized ushort4), writes transposed bf16 into xzT.
__global__ __launch_bounds__(256) void fold_kernel(
    const ushort* __restrict__ xb, const float* __restrict__ Z,
    ushort* __restrict__ xzT) {
    __shared__ float tile[64][65];
    __shared__ float zin[64];
    const int b = blockIdx.y;
    const int td = blockIdx.x & 7;    // d-tile (512/64 = 8)
    const int tn = blockIdx.x >> 3;   // n-tile (2048/64 = 32)
    const int n0 = tn * 64, d0 = td * 64;
    const int t = threadIdx.x;
    if (t < 64) zin[t] = 1.0f / Z[b * 2048 + n0 + t];
    __syncthreads();
    const int c4 = (t & 15) * 4, rr = t >> 4;
#pragma unroll
    for (int j = 0; j < 4; ++j) {
        int nr = rr + j * 16;
        ushort4 v = *(const ushort4*)&xb[((size_t)b * 2048 + n0 + nr) * 512 + d0 + c4];
        float zi = zin[nr];
        tile[nr][c4 + 0] = bf2f(v.x) * zi;
        tile[nr][c4 + 1] = bf2f(v.y) * zi;
        tile[nr][c4 + 2] = bf2f(v.z) * zi;
        tile[nr][c4 + 3] = bf2f(v.w) * zi;
    }
    __syncthreads();
#pragma unroll
    for (int j = 0; j < 4; ++j) {
        int dr = rr + j * 16;
        ushort4 r;
        r.x = f2bf(tile[c4 + 0][dr]);
        r.y = f2bf(tile[c4 + 1][dr]);
        r.z = f2bf(tile[c4 + 2][dr]);
        r.w = f2bf(tile[c4 + 3][dr]);
        *(ushort4*)&xzT[((size_t)b * 512 + d0 + dr) * 2048 + n0 + c4] = r;
    }
}

// ---------------- bt-GEMM (32x32x16 MFMA): C[m,n] = sum_k A[m,k]*B[n,k] ----
// 128x128 tile, BK=64, 4 waves (2x2), wave tile 64x64 = 2x2 MFMA tiles.
// LDS [128 rows][64 k] bf16, swizzle involution: kbyte ^= ((row&7)<<4),
// applied on the global SOURCE of global_load_lds and on the ds_read col.
// EPI 0: +bias[n], bf16 | EPI 1: exp(acc*scale), bf16 + Z col-sums | EPI 2: f32
template <int EPI>
__global__ __launch_bounds__(256) void gemm_bt32(
    const ushort* __restrict__ A, int lda, long sA,
    const ushort* __restrict__ B, int ldb, long sB,
    void* __restrict__ C, int ldc, long sC,
    int tiles_n, int K,
    const float* __restrict__ bias, float scale,
    float* __restrict__ Z, long sZ) {
    __shared__ ushort lA[128 * 64];  // 16 KB
    __shared__ ushort lB[128 * 64];  // 16 KB
    const int b = blockIdx.y;
    A += (size_t)b * sA;
    B += (size_t)b * sB;
    const int tm = blockIdx.x / tiles_n, tn = blockIdx.x % tiles_n;
    const int t = threadIdx.x;
    const int l = t & 63, w = t >> 6;
    const int wr = w >> 1, wc = w & 1;  // 2x2 waves, each 64x64

    f32x16 acc[2][2];
#pragma unroll
    for (int i = 0; i < 2; ++i)
#pragma unroll
        for (int j = 0; j < 2; ++j)
#pragma unroll
            for (int q = 0; q < 16; ++q) acc[i][j][q] = 0.f;

    // per-thread staging pattern (linear LDS dest, pre-swizzled global src)
    const int soff = t * 16;  // + p*4096
    const int srow0 = soff >> 7;
    const int skb = soff & 127;

    for (int k0 = 0; k0 < K; k0 += 64) {
#pragma unroll
        for (int p = 0; p < 4; ++p) {
            int off = p * 4096 + soff;
            int row = srow0 + p * 32;
            int kswz = skb ^ ((row & 7) << 4);
            async_copy16(A + (size_t)(tm * 128 + row) * lda + k0 + (kswz >> 1),
                         (char*)lA + off);
            async_copy16(B + (size_t)(tn * 128 + row) * ldb + k0 + (kswz >> 1),
                         (char*)lB + off);
        }
        __syncthreads();
#pragma unroll
        for (int ksx = 0; ksx < 4; ++ksx) {
            bf16x8 af[2], bfr[2];
#pragma unroll
            for (int rb = 0; rb < 2; ++rb) {
                int row = wr * 64 + rb * 32 + (l & 31);
                int colb = (ksx * 32 + (l >> 5) * 16) ^ ((row & 7) << 4);
                af[rb] = *(const bf16x8*)((const char*)lA + row * 128 + colb);
            }
#pragma unroll
            for (int cb = 0; cb < 2; ++cb) {
                int row = wc * 64 + cb * 32 + (l & 31);
                int colb = (ksx * 32 + (l >> 5) * 16) ^ ((row & 7) << 4);
                bfr[cb] = *(const bf16x8*)((const char*)lB + row * 128 + colb);
            }
#pragma unroll
            for (int rb = 0; rb < 2; ++rb)
#pragma unroll
                for (int cb = 0; cb < 2; ++cb)
                    acc[rb][cb] = __builtin_amdgcn_mfma_f32_32x32x16_bf16(
                        af[rb], bfr[cb], acc[rb][cb], 0, 0, 0);
        }
        __syncthreads();
    }

    const int mb = tm * 128 + wr * 64;
    const int nb = tn * 128 + wc * 64;
    // C/D map (m74/m101): col = lane&31, row = (reg&3) + 8*(reg>>2) + 4*(lane>>5)
    const int rbase = 4 * (l >> 5);
    const int cl = l & 31;

    if (EPI == 0) {
        ushort* Cp = (ushort*)C + (size_t)b * sC;
#pragma unroll
        for (int rb = 0; rb < 2; ++rb)
#pragma unroll
            for (int cb = 0; cb < 2; ++cb) {
                int col = nb + cb * 32 + cl;
                float bv = bias[col];
#pragma unroll
                for (int reg = 0; reg < 16; ++reg) {
                    int row = mb + rb * 32 + (reg & 3) + 8 * (reg >> 2) + rbase;
                    Cp[(size_t)row * ldc + col] = f2bf(acc[rb][cb][reg] + bv);
                }
            }
    } else if (EPI == 1) {
        ushort* Cp = (ushort*)C + (size_t)b * sC;
        float cs[2] = {0.f, 0.f};
#pragma unroll
        for (int rb = 0; rb < 2; ++rb)
#pragma unroll
            for (int cb = 0; cb < 2; ++cb) {
                int col = nb + cb * 32 + cl;
#pragma unroll
                for (int reg = 0; reg < 16; ++reg) {
                    int row = mb + rb * 32 + (reg & 3) + 8 * (reg >> 2) + rbase;
                    float e = __expf(acc[rb][cb][reg] * scale);
                    Cp[(size_t)row * ldc + col] = f2bf(e);
                    cs[cb] += e;
                }
            }
#pragma unroll
        for (int cb = 0; cb < 2; ++cb) {
            float s = cs[cb];
            s += __shfl_xor(s, 32);
            if (l < 32) atomicAdd(&Z[b * sZ + nb + cb * 32 + cl], s);
        }
    } else {
        float* Cp = (float*)C + (size_t)b * sC;
#pragma unroll
        for (int rb = 0; rb < 2; ++rb)
#pragma unroll
            for (int cb = 0; cb < 2; ++cb) {
                int col = nb + cb * 32 + cl;
#pragma unroll
                for (int reg = 0; reg < 16; ++reg) {
                    int row = mb + rb * 32 + (reg & 3) + 8 * (reg >> 2) + rbase;
                    Cp[(size_t)row * ldc + col] = acc[rb][cb][reg];
                }
            }
    }
}

extern "C" void kernel_launch(void* const* d_in, const int* in_sizes, int n_in,
                              void* d_out, int out_size, void* d_ws, size_t ws_size,
                              hipStream_t stream) {
    const float* x  = (const float*)d_in[0];
    const float* Wq = (const float*)d_in[1];
    const float* bq = (const float*)d_in[2];
    const float* Wk = (const float*)d_in[3];
    const float* bk = (const float*)d_in[4];

    char* ws = (char*)d_ws;
    ushort* xb    = (ushort*)(ws);                 // 16 MB
    ushort* Wb    = (ushort*)(ws + 16777216);      //  1 MB
    float*  biasc = (float*) (ws + 17825792);      //  4 KB
    float*  Z     = (float*) (ws + 17829888);      // 64 KB
    ushort* qkb   = (ushort*)(ws + 17895424);      // 32 MB (reused as xzT after E-pass)
    ushort* E     = (ushort*)(ws + 51449856);      // 64 MB
    ushort* xzT   = qkb;   // qkb is dead once the E-pass completes

    hipMemsetAsync(Z, 0, 16384 * 4, stream);

    cvt_kernel<<<8192, 256, 0, stream>>>(
        (const float4*)x, (const float4*)Wq, (const float4*)Wk,
        (const float4*)bq, (const float4*)bk,
        (ushort4*)xb, (ushort4*)Wb, (float4*)biasc);

    // proj: qk[m, 0:1024] = x[m,:] . W[h,:] + bias   (M=16384, N=1024, K=512)
    gemm_bt32<0><<<dim3(1024, 1), 256, 0, stream>>>(
        xb, 512, 0L, Wb, 512, 0L, qkb, 1024, 0L,
        8, 512, biasc, 0.f, nullptr, 0L);

    // E-pass: E[b][m][n] = exp(scale * k[m].q[n]); Z[b][n] += column sums
    gemm_bt32<1><<<dim3(256, 8), 256, 0, stream>>>(
        qkb + 512, 1024, 2048L * 1024, qkb, 1024, 2048L * 1024,
        E, 2048, 2048L * 2048, 16, 512,
        nullptr, 0.04419417382415922f, Z, 2048L);

    // fold: xzT[b][d][n] = bf16(xb[b][n][d] / Z[b][n])
    fold_kernel<<<dim3(256, 8), 256, 0, stream>>>(xb, Z, xzT);

    // out: out[b][m][d] = sum_n E[b][m][n] * xzT[b][d][n]   (fp32 store)
    gemm_bt32<2><<<dim3(64, 8), 256, 0, stream>>>(
        E, 2048, 2048L * 2048, xzT, 2048, 512L * 2048,
        d_out, 512, 2048L * 512, 4, 2048,
        nullptr, 0.f, nullptr, 0L);
}

// Round 4
// 153.704 us; speedup vs baseline: 1.0174x; 1.0009x over previous
//
#include <hip/hip_runtime.h>

typedef __bf16 bf16x8 __attribute__((ext_vector_type(8)));
typedef float f32x4 __attribute__((ext_vector_type(4)));

__device__ __forceinline__ ushort f2bf(float f) {
    union { float f; unsigned u; } v; v.f = f;
    unsigned r = v.u + 0x7FFF + ((v.u >> 16) & 1);
    return (ushort)(r >> 16);
}
__device__ __forceinline__ float bf2f(ushort u) {
    union { unsigned u; float f; } v; v.u = ((unsigned)u) << 16;
    return v.f;
}

__device__ __forceinline__ void async_copy16(const void* g, void* l) {
    __builtin_amdgcn_global_load_lds(
        (const __attribute__((address_space(1))) void*)g,
        (__attribute__((address_space(3))) void*)l, 16, 0, 0);
}

// ---------------- cvt: x -> bf16, [Wq;Wk] -> bf16, [bq;bk] -> f32 concat ----
__global__ __launch_bounds__(256) void cvt_kernel(
    const float4* __restrict__ x, const float4* __restrict__ Wq,
    const float4* __restrict__ Wk, const float4* __restrict__ bq,
    const float4* __restrict__ bk,
    ushort4* __restrict__ xb, ushort4* __restrict__ Wb,
    float4* __restrict__ biasc) {
    int i = blockIdx.x * 256 + threadIdx.x;
    if (i < 2097152) {
        float4 v = x[i];
        ushort4 r; r.x = f2bf(v.x); r.y = f2bf(v.y); r.z = f2bf(v.z); r.w = f2bf(v.w);
        xb[i] = r;
    }
    if (i < 131072) {
        float4 v = (i < 65536) ? Wq[i] : Wk[i - 65536];
        ushort4 r; r.x = f2bf(v.x); r.y = f2bf(v.y); r.z = f2bf(v.z); r.w = f2bf(v.w);
        Wb[i] = r;
    }
    if (i < 256) {
        biasc[i] = (i < 128) ? bq[i] : bk[i - 128];
    }
}

// ---------------- fold: xzT[b][d][n] = bf16(xb[b][n][d] / Z[b][n]) ---------
__global__ __launch_bounds__(256) void fold_kernel(
    const ushort* __restrict__ xb, const float* __restrict__ Z,
    ushort* __restrict__ xzT) {
    __shared__ float tile[64][65];
    __shared__ float zin[64];
    const int b = blockIdx.y;
    const int td = blockIdx.x & 7;    // d-tile (512/64 = 8)
    const int tn = blockIdx.x >> 3;   // n-tile (2048/64 = 32)
    const int n0 = tn * 64, d0 = td * 64;
    const int t = threadIdx.x;
    if (t < 64) zin[t] = 1.0f / Z[b * 2048 + n0 + t];
    __syncthreads();
    const int c4 = (t & 15) * 4, rr = t >> 4;
#pragma unroll
    for (int j = 0; j < 4; ++j) {
        int nr = rr + j * 16;
        ushort4 v = *(const ushort4*)&xb[((size_t)b * 2048 + n0 + nr) * 512 + d0 + c4];
        float zi = zin[nr];
        tile[nr][c4 + 0] = bf2f(v.x) * zi;
        tile[nr][c4 + 1] = bf2f(v.y) * zi;
        tile[nr][c4 + 2] = bf2f(v.z) * zi;
        tile[nr][c4 + 3] = bf2f(v.w) * zi;
    }
    __syncthreads();
#pragma unroll
    for (int j = 0; j < 4; ++j) {
        int dr = rr + j * 16;
        ushort4 r;
        r.x = f2bf(tile[c4 + 0][dr]);
        r.y = f2bf(tile[c4 + 1][dr]);
        r.z = f2bf(tile[c4 + 2][dr]);
        r.w = f2bf(tile[c4 + 3][dr]);
        *(ushort4*)&xzT[((size_t)b * 512 + d0 + dr) * 2048 + n0 + c4] = r;
    }
}

// ---------------- 2-phase dbuf bt-GEMM: C[m,n] = sum_k A[m,k]*B[n,k] -------
// 128x128 tile, BK=64, 4 waves (2x2), 16x16x32 MFMA, 4x4 frags/wave.
// Double-buffered LDS (2 x 16KB per operand = 64 KB). Per K-step:
//   STAGE(next buf) issued FIRST -> frag reads + MFMA on current buf ->
//   one __syncthreads() (compiler's vmcnt(0)+lgkmcnt(0) drain sits AFTER the
//   compute window, so stage latency is hidden under MFMA+ds_read).
// Swizzle involution both sides: kbyte ^= ((row&7)<<4) (pre-swizzled global
// source, linear LDS dest, swizzled ds_read col). 16-lane frag rows -> 2-way
// bank aliasing only (free).
// EPI 0: +bias[n], bf16 | EPI 1: exp(acc*scale), bf16 + Z col-sums | EPI 2: f32
template <int EPI>
__global__ __launch_bounds__(256) void gemm_db(
    const ushort* __restrict__ A, int lda, long sA,
    const ushort* __restrict__ B, int ldb, long sB,
    void* __restrict__ C, int ldc, long sC,
    int tiles_n, int K,
    const float* __restrict__ bias, float scale,
    float* __restrict__ Z, long sZ) {
    __shared__ ushort lA[2][8192];  // 2 x 16 KB
    __shared__ ushort lB[2][8192];  // 2 x 16 KB
    const int b = blockIdx.y;
    A += (size_t)b * sA;
    B += (size_t)b * sB;
    const int tm = blockIdx.x / tiles_n, tn = blockIdx.x % tiles_n;
    const int t = threadIdx.x;
    const int l = t & 63, w = t >> 6;
    const int wr = w >> 1, wc = w & 1;  // 2x2 waves, each 64x64

    // per-thread staging pattern (linear LDS dest, pre-swizzled global src)
    size_t gA[4], gB[4];
    int dOf[4];
#pragma unroll
    for (int p = 0; p < 4; ++p) {
        int off = p * 4096 + t * 16;       // byte offset within one 16KB buf
        int row = off >> 7;                // 0..127
        int kb = off & 127;
        int kswz = kb ^ ((row & 7) << 4);  // involution
        gA[p] = (size_t)(tm * 128 + row) * lda + (kswz >> 1);
        gB[p] = (size_t)(tn * 128 + row) * ldb + (kswz >> 1);
        dOf[p] = off;
    }

    auto stage = [&](int buf, int k0) {
#pragma unroll
        for (int p = 0; p < 4; ++p) {
            async_copy16(A + gA[p] + k0, (char*)lA[buf] + dOf[p]);
            async_copy16(B + gB[p] + k0, (char*)lB[buf] + dOf[p]);
        }
    };

    f32x4 acc[4][4];
#pragma unroll
    for (int i = 0; i < 4; ++i)
#pragma unroll
        for (int j = 0; j < 4; ++j) acc[i][j] = (f32x4){0.f, 0.f, 0.f, 0.f};

    stage(0, 0);
    __syncthreads();

    const int nk = K >> 6;
    for (int kt = 0; kt < nk; ++kt) {
        const int cur = kt & 1;
        if (kt + 1 < nk) stage(cur ^ 1, (kt + 1) << 6);
        __builtin_amdgcn_sched_barrier(0);  // keep stage-issue ahead of compute
#pragma unroll
        for (int ks = 0; ks < 2; ++ks) {
            bf16x8 af[4], bfr[4];
#pragma unroll
            for (int i = 0; i < 4; ++i) {
                int row = wr * 64 + i * 16 + (l & 15);
                int colb = (ks * 64 + (l >> 4) * 16) ^ ((row & 7) << 4);
                af[i] = *(const bf16x8*)((const char*)lA[cur] + row * 128 + colb);
            }
#pragma unroll
            for (int j = 0; j < 4; ++j) {
                int row = wc * 64 + j * 16 + (l & 15);
                int colb = (ks * 64 + (l >> 4) * 16) ^ ((row & 7) << 4);
                bfr[j] = *(const bf16x8*)((const char*)lB[cur] + row * 128 + colb);
            }
#pragma unroll
            for (int i = 0; i < 4; ++i)
#pragma unroll
                for (int j = 0; j < 4; ++j)
                    acc[i][j] = __builtin_amdgcn_mfma_f32_16x16x32_bf16(
                        af[i], bfr[j], acc[i][j], 0, 0, 0);
        }
        __syncthreads();  // drains this iter's stage loads + all ds_reads
    }

    const int mb = tm * 128 + wr * 64;
    const int nb = tn * 128 + wc * 64;

    if (EPI == 0) {
        ushort* Cp = (ushort*)C + (size_t)b * sC;
#pragma unroll
        for (int i = 0; i < 4; ++i)
#pragma unroll
            for (int j = 0; j < 4; ++j)
#pragma unroll
                for (int q = 0; q < 4; ++q) {
                    int row = mb + i * 16 + (l >> 4) * 4 + q;
                    int col = nb + j * 16 + (l & 15);
                    Cp[(size_t)row * ldc + col] = f2bf(acc[i][j][q] + bias[col]);
                }
    } else if (EPI == 1) {
        ushort* Cp = (ushort*)C + (size_t)b * sC;
        float colsum[4] = {0.f, 0.f, 0.f, 0.f};
#pragma unroll
        for (int i = 0; i < 4; ++i)
#pragma unroll
            for (int j = 0; j < 4; ++j)
#pragma unroll
                for (int q = 0; q < 4; ++q) {
                    int row = mb + i * 16 + (l >> 4) * 4 + q;
                    int col = nb + j * 16 + (l & 15);
                    float e = __expf(acc[i][j][q] * scale);
                    Cp[(size_t)row * ldc + col] = f2bf(e);
                    colsum[j] += e;
                }
#pragma unroll
        for (int j = 0; j < 4; ++j) {
            float s = colsum[j];
            s += __shfl_xor(s, 16);
            s += __shfl_xor(s, 32);
            if (l < 16) atomicAdd(&Z[b * sZ + nb + j * 16 + l], s);
        }
    } else {
        float* Cp = (float*)C + (size_t)b * sC;
#pragma unroll
        for (int i = 0; i < 4; ++i)
#pragma unroll
            for (int j = 0; j < 4; ++j)
#pragma unroll
                for (int q = 0; q < 4; ++q) {
                    int row = mb + i * 16 + (l >> 4) * 4 + q;
                    int col = nb + j * 16 + (l & 15);
                    Cp[(size_t)row * ldc + col] = acc[i][j][q];
                }
    }
}

extern "C" void kernel_launch(void* const* d_in, const int* in_sizes, int n_in,
                              void* d_out, int out_size, void* d_ws, size_t ws_size,
                              hipStream_t stream) {
    const float* x  = (const float*)d_in[0];
    const float* Wq = (const float*)d_in[1];
    const float* bq = (const float*)d_in[2];
    const float* Wk = (const float*)d_in[3];
    const float* bk = (const float*)d_in[4];

    char* ws = (char*)d_ws;
    ushort* xb    = (ushort*)(ws);                 // 16 MB
    ushort* Wb    = (ushort*)(ws + 16777216);      //  1 MB
    float*  biasc = (float*) (ws + 17825792);      //  4 KB
    float*  Z     = (float*) (ws + 17829888);      // 64 KB
    ushort* qkb   = (ushort*)(ws + 17895424);      // 32 MB (reused as xzT after E-pass)
    ushort* E     = (ushort*)(ws + 51449856);      // 64 MB
    ushort* xzT   = qkb;   // qkb is dead once the E-pass completes

    hipMemsetAsync(Z, 0, 16384 * 4, stream);

    cvt_kernel<<<8192, 256, 0, stream>>>(
        (const float4*)x, (const float4*)Wq, (const float4*)Wk,
        (const float4*)bq, (const float4*)bk,
        (ushort4*)xb, (ushort4*)Wb, (float4*)biasc);

    // proj: qk[m, 0:1024] = x[m,:] . W[h,:] + bias   (M=16384, N=1024, K=512)
    gemm_db<0><<<dim3(1024, 1), 256, 0, stream>>>(
        xb, 512, 0L, Wb, 512, 0L, qkb, 1024, 0L,
        8, 512, biasc, 0.f, nullptr, 0L);

    // E-pass: E[b][m][n] = exp(scale * k[m].q[n]); Z[b][n] += column sums
    gemm_db<1><<<dim3(256, 8), 256, 0, stream>>>(
        qkb + 512, 1024, 2048L * 1024, qkb, 1024, 2048L * 1024,
        E, 2048, 2048L * 2048, 16, 512,
        nullptr, 0.04419417382415922f, Z, 2048L);

    // fold: xzT[b][d][n] = bf16(xb[b][n][d] / Z[b][n])
    fold_kernel<<<dim3(256, 8), 256, 0, stream>>>(xb, Z, xzT);

    // out: out[b][m][d] = sum_n E[b][m][n] * xzT[b][d][n]   (fp32 store)
    gemm_db<2><<<dim3(64, 8), 256, 0, stream>>>(
        E, 2048, 2048L * 2048, xzT, 2048, 512L * 2048,
        d_out, 512, 2048L * 512, 4, 2048,
        nullptr, 0.f, nullptr, 0L);
}